// Round 9
// baseline (338.472 us; speedup 1.0000x reference)
//
#include <hip/hip_runtime.h>
#include <stdint.h>

// Problem: out[m][n] = sum_k x[m][k] * w[n][k] + bias[n]
//   M=256, N=16384, K=4096, w = dequant(2-bit, group=16 along k)
// Round 9: SINGLE KERNEL. The separate cvt_x_kernel (and its workspace) is
// eliminated: every round showed a constant ~85-90us gap between total and
// gemm dispatch time, and cvt is the only unchanged serial component. The
// A-fragment is 8 consecutive fp32 of one x row, so the gemm loads 2x float4
// from x directly and packs to bf16 in registers (same f2bf RNE math).
// Otherwise the round-3 best structure (76us): BM=128/BN=64/BK=64, grid
// (256,2), 8 waves = 4m x 2n, B-only LDS dbuf + XOR swizzle, lgkm-only
// barrier, q2/norm prefetch 2 bodies deep, direct epilogue with bias.
#define M_DIM 256
#define N_DIM 16384
#define K_DIM 4096
#define BN 64
#define BK 64
#define NT (K_DIM / BK)   // 64 k-tiles

typedef __bf16 bf16x8 __attribute__((ext_vector_type(8)));
typedef float  f32x4  __attribute__((ext_vector_type(4)));

// fp32 -> bf16 bits, round-nearest-even (finite inputs)
__device__ __forceinline__ uint32_t f2bf(float f) {
  uint32_t u = __float_as_uint(f);
  return (u + 0x7fffu + ((u >> 16) & 1u)) >> 16;
}

// pack 8 fp32 (two float4) -> 8 bf16 in a uint4 (A-fragment order)
__device__ __forceinline__ uint4 packbf8(float4 a, float4 b) {
  uint4 o;
  o.x = f2bf(a.x) | (f2bf(a.y) << 16);
  o.y = f2bf(a.z) | (f2bf(a.w) << 16);
  o.z = f2bf(b.x) | (f2bf(b.y) << 16);
  o.w = f2bf(b.z) | (f2bf(b.w) << 16);
  return o;
}

// Barrier that waits ONLY on LDS ops (dbuf ordering) -- global prefetches
// stay in flight across it.
#define LDS_BARRIER() \
  asm volatile("s_waitcnt lgkmcnt(0)\n\ts_barrier" ::: "memory")

// ---------------------------------------------------------------------------
// Dequant 8 elems (2 packed q2 words; 4 crumbs in each low byte) of one group.
// Table entries {-n, a-n, 2a-n, 3a-n}, a = n*2/3 -- bit-identical to the
// fmaf+f2bf reference path.  v_perm_b32 picks the bf16 entry per crumb.
// ---------------------------------------------------------------------------
__device__ __forceinline__ uint4 deq8(uint2 q, float nv) {
  float a2 = nv * (2.0f / 3.0f);
  uint32_t tlo = f2bf(-nv) | (f2bf(fmaf(1.0f, a2, -nv)) << 16);
  uint32_t thi = f2bf(fmaf(2.0f, a2, -nv)) | (f2bf(fmaf(3.0f, a2, -nv)) << 16);
  uint32_t s0 = ((q.x & 3u) | ((q.x & 0xCu) << 14)) * 0x0202u + 0x01000100u;
  uint32_t s1 = (((q.x >> 4) & 3u) | ((q.x & 0xC0u) << 10)) * 0x0202u + 0x01000100u;
  uint32_t s2 = ((q.y & 3u) | ((q.y & 0xCu) << 14)) * 0x0202u + 0x01000100u;
  uint32_t s3 = (((q.y >> 4) & 3u) | ((q.y & 0xC0u) << 10)) * 0x0202u + 0x01000100u;
  uint4 r;
  r.x = __builtin_amdgcn_perm(thi, tlo, s0);
  r.y = __builtin_amdgcn_perm(thi, tlo, s1);
  r.z = __builtin_amdgcn_perm(thi, tlo, s2);
  r.w = __builtin_amdgcn_perm(thi, tlo, s3);
  return r;
}

// ---------------------------------------------------------------------------
// Kernel: grid (256,2), 512 threads. Wave w: wm=w>>1 (32 m-rows), wn=w&1
// (32 n-cols). Body T: issue fp32 A(T+1) loads (8x dwordx4 -> raw regs);
// 8 MFMA on packed A(T) + LDS B(T); dequant tile T+1 (q loaded 2 bodies ago)
// into Bb[p^1]; reload q(T+3); pack raw->A(T+1); lgkm-only barrier.
// ---------------------------------------------------------------------------
__global__ __launch_bounds__(512, 4) void gemm2bit_kernel(
    const float*    __restrict__ x,    // [256][4096] fp32
    const uint32_t* __restrict__ q2,   // [G][4] packed 2-bit (low byte crumbs)
    const float*    __restrict__ nrm,  // [G] group norms (f32)
    const float*    __restrict__ bias, // [N]
    float*          __restrict__ out)  // [256][16384] fp32
{
  __shared__ uint4 Bb[2][512];  // 8 chunks (ts*4+nb) x 64 slots, dbuf = 16 KiB

  const int tid  = threadIdx.x;
  const int lane = tid & 63;
  const int w    = tid >> 6;    // 0..7
  const int wm   = w >> 1;      // 0..3 : rows m0 + wm*32 .. +31
  const int wn   = w & 1;       // 0..1 : cols n0 + wn*32 .. +31
  const int lo4  = lane & 15;
  const int qd   = lane >> 4;
  const int n0   = blockIdx.x * BN;
  const int m0   = blockIdx.y * 128;

  // swizzled read lane: XOR qd into low 2 bits of lo4 (matches write swizzle)
  const int lrs = lane ^ qd;    // qd in 0..3, touches bits 0..1 only

  // --- B staging role: one half-group (8 elems) per thread ---
  const int nloc = tid >> 3;          // 0..63 n-row within tile
  const int kg   = (tid >> 1) & 3;    // k-group (16 elems) within BK
  const int h    = tid & 1;           // which half of the group
  const int grow = n0 + nloc;
  // logical slot: chunk cb = (kg>>1)*4 + (nloc>>4); within: qd2 = (kg&1)*2+h
  const int qd2   = (kg & 1) * 2 + h;
  const int bslot = ((kg >> 1) * 4 + (nloc >> 4)) * 64 + qd2 * 16 +
                    ((nloc & 15) ^ qd2);   // phys = logical ^ qd2

  // --- pointers ---
  // A fragment source (fp32, converted inline): lane l of m-chunk (wm*2+s)
  // reads x[m0 + (wm*2+s)*16 + (l&15)][kch*32 + (l>>4)*8 .. +7]
  const float* pX0 = x + (size_t)(m0 + (wm * 2 + 0) * 16 + lo4) * K_DIM + qd * 8;
  const float* pX1 = x + (size_t)(m0 + (wm * 2 + 1) * 16 + lo4) * K_DIM + qd * 8;
  // q2: group gidx = grow*256 + t*4 + kg; uint2 at gidx*4 + h*2
  const uint32_t* pq = q2 + ((size_t)grow * 256 + kg) * 4 + h * 2;
  const float*    pn = nrm + (size_t)grow * 256 + kg;

  f32x4 acc[2][2];
#pragma unroll
  for (int s = 0; s < 2; ++s)
#pragma unroll
    for (int u = 0; u < 2; ++u)
      acc[s][u] = (f32x4){0.f, 0.f, 0.f, 0.f};

  float4 raw[4][2];        // fp32 staging for A(T+1), static-indexed only
  uint4  apkE[4], apkO[4]; // packed bf16 A fragments [s*2+ts], ping-pong
  uint2 qA, qB;
  float nA, nB;

  // ---- prologue: A(0) load+pack; tile0 B dequant; q(1),q(2) prefetched ----
#pragma unroll
  for (int s = 0; s < 2; ++s) {
    const float* px = s ? pX1 : pX0;
#pragma unroll
    for (int ts = 0; ts < 2; ++ts) {
      float4 f0 = *(const float4*)(px + ts * 32);
      float4 f1 = *(const float4*)(px + ts * 32 + 4);
      apkE[s * 2 + ts] = packbf8(f0, f1);
    }
  }
  uint2 q0 = *(const uint2*)pq;
  float n0v = pn[0];
  qA = *(const uint2*)(pq + 16);      // q(1), consumed body 0
  nA = pn[4];
  qB = *(const uint2*)(pq + 32);      // q(2), consumed body 1
  nB = pn[8];
  Bb[0][bslot] = deq8(q0, n0v);
  LDS_BARRIER();

  // Body T: issue A(T+1) fp32 loads; MFMA tile T from Bb[PR]+APK; dequant
  // tile T+1 from QC (loaded at T-2) into Bb[PR^1]; reload QC=q(T+3);
  // pack raw -> APKN; barrier.
#define GEMM_BODY(T, PR, APK, APKN, QC, NC)                                     \
  do {                                                                          \
    if ((T) + 1 < NT) {                                                         \
      _Pragma("unroll")                                                         \
      for (int s = 0; s < 2; ++s) {                                             \
        const float* px = s ? pX1 : pX0;                                        \
        _Pragma("unroll")                                                       \
        for (int ts = 0; ts < 2; ++ts) {                                        \
          raw[s * 2 + ts][0] = *(const float4*)(px + ((T) + 1) * 64 + ts * 32); \
          raw[s * 2 + ts][1] =                                                  \
              *(const float4*)(px + ((T) + 1) * 64 + ts * 32 + 4);              \
        }                                                                       \
      }                                                                         \
    }                                                                           \
    _Pragma("unroll")                                                           \
    for (int ts = 0; ts < 2; ++ts) {                                            \
      bf16x8 bfv[2];                                                            \
      _Pragma("unroll")                                                         \
      for (int u = 0; u < 2; ++u)                                               \
        bfv[u] = *(const bf16x8*)&Bb[PR][(ts * 4 + wn * 2 + u) * 64 + lrs];     \
      _Pragma("unroll")                                                         \
      for (int s = 0; s < 2; ++s) {                                             \
        bf16x8 av = __builtin_bit_cast(bf16x8, APK[s * 2 + ts]);                \
        _Pragma("unroll")                                                       \
        for (int u = 0; u < 2; ++u)                                             \
          acc[s][u] = __builtin_amdgcn_mfma_f32_16x16x32_bf16(av, bfv[u],       \
                                                              acc[s][u], 0, 0, 0);\
      }                                                                         \
    }                                                                           \
    if ((T) + 1 < NT) Bb[(PR) ^ 1][bslot] = deq8(QC, NC);                       \
    if ((T) + 3 < NT) {                                                         \
      QC = *(const uint2*)(pq + (size_t)((T) + 3) * 16);                        \
      NC = pn[(size_t)((T) + 3) * 4];                                           \
    }                                                                           \
    if ((T) + 1 < NT) {                                                         \
      _Pragma("unroll")                                                         \
      for (int j = 0; j < 4; ++j) APKN[j] = packbf8(raw[j][0], raw[j][1]);      \
    }                                                                           \
    LDS_BARRIER();                                                              \
  } while (0)

  for (int t2 = 0; t2 < NT; t2 += 2) {
    GEMM_BODY(t2,     0, apkE, apkO, qA, nA);
    GEMM_BODY(t2 + 1, 1, apkO, apkE, qB, nB);
  }
#undef GEMM_BODY

  // ---- epilogue: direct store, C/D layout col=lane&15 (n),
  // row=(lane>>4)*4+reg (m) ----
  float bv[2];
#pragma unroll
  for (int u = 0; u < 2; ++u)
    bv[u] = bias[n0 + wn * 32 + u * 16 + lo4];

#pragma unroll
  for (int s = 0; s < 2; ++s) {
    int mrow = m0 + wm * 32 + s * 16 + qd * 4;
#pragma unroll
    for (int u = 0; u < 2; ++u) {
      int ncol = n0 + wn * 32 + u * 16 + lo4;
      float* p = out + (size_t)mrow * N_DIM + ncol;
#pragma unroll
      for (int r = 0; r < 4; ++r)
        p[(size_t)r * N_DIM] = acc[s][u][r] + bv[u];
    }
  }
}

// ---------------------------------------------------------------------------
extern "C" void kernel_launch(void* const* d_in, const int* in_sizes, int n_in,
                              void* d_out, int out_size, void* d_ws, size_t ws_size,
                              hipStream_t stream) {
  const float*    x    = (const float*)d_in[0];
  const uint32_t* q2   = (const uint32_t*)d_in[1];
  const float*    nm   = (const float*)d_in[2];
  const float*    bias = (const float*)d_in[3];
  float*          out  = (float*)d_out;
  (void)d_ws; (void)ws_size;

  gemm2bit_kernel<<<dim3(N_DIM / BN, 2), 512, 0, stream>>>(x, q2, nm, bias, out);
}

// Round 10
// 153.948 us; speedup vs baseline: 2.1986x; 2.1986x over previous
//
#include <hip/hip_runtime.h>
#include <stdint.h>

// Problem: out[m][n] = sum_k x[m][k] * w[n][k] + bias[n]
//   M=256, N=16384, K=4096, w = dequant(2-bit, group=16 along k)
// Round 10: PRODUCER/CONSUMER wave specialization on the round-3 skeleton
// (best: 76us). Grid (256,2), 512 thr, BM=128/BN=64/BK=64, 16KB LDS dbuf,
// XOR swizzle, lgkm-only barrier, A via coalesced fragment workspace.
//  - waves 0..3 = CONSUMERS: each 32m x 64n; 8 ds_read_b128 + 16 MFMA/body;
//    A(T+1) reg-prefetch; setprio(1) around the MFMA cluster (role diversity
//    now exists on the CU, so T5's prerequisite holds).
//  - waves 4..7 = PRODUCERS: each lane owns one 16-elem group of tile T+1:
//    one uint4 q2 load (16 segments x 64B, fully used) + nrm load + 2 deq8 +
//    2 swizzled ds_write_b128; q2/nrm prefetched 2 bodies deep.
// Dequant VALU and MFMA now live on DIFFERENT waves -> the SIMD co-schedules
// them (MFMA+VALU overlap = max, not sum) instead of serializing the chain
// inside every wave between lockstep barriers.
#define M_DIM 256
#define N_DIM 16384
#define K_DIM 4096
#define BN 64
#define BK 64
#define NT (K_DIM / BK)   // 64 k-tiles

typedef __bf16 bf16x8 __attribute__((ext_vector_type(8)));
typedef float  f32x4  __attribute__((ext_vector_type(4)));

// fp32 -> bf16 bits, round-nearest-even (finite inputs)
__device__ __forceinline__ uint32_t f2bf(float f) {
  uint32_t u = __float_as_uint(f);
  return (u + 0x7fffu + ((u >> 16) & 1u)) >> 16;
}

// Barrier that waits ONLY on LDS ops (dbuf ordering) -- global prefetches
// stay in flight across it.
#define LDS_BARRIER() \
  asm volatile("s_waitcnt lgkmcnt(0)\n\ts_barrier" ::: "memory")

// ---------------------------------------------------------------------------
// Kernel 1: x fp32 [256][4096] -> bf16 fragment-chunk order (unchanged).
// Chunk = (m-block of 16 rows) x (k-chunk of 32): 64 slots x 16B.
// Slot L holds row (L&15), k = (L>>4)*8 .. +7  (MFMA 16x16x32 A-frag order).
// ws uint4 index = (mb_glob*128 + kch)*64 + L.
// ---------------------------------------------------------------------------
__global__ __launch_bounds__(256) void cvt_x_kernel(const float* __restrict__ x,
                                                    uint4* __restrict__ ws) {
  int T = blockIdx.x * 256 + threadIdx.x;       // 0..131071
  int mb_glob = T >> 13;                        // 16 m-blocks
  int r       = T & 8191;
  int kch     = r >> 6;                         // 128 k-chunks
  int L       = r & 63;
  int row = mb_glob * 16 + (L & 15);
  int k   = kch * 32 + (L >> 4) * 8;
  const float* p = x + (size_t)row * K_DIM + k;
  float4 a = *(const float4*)p;
  float4 b = *(const float4*)(p + 4);
  uint4 o;
  o.x = f2bf(a.x) | (f2bf(a.y) << 16);
  o.y = f2bf(a.z) | (f2bf(a.w) << 16);
  o.z = f2bf(b.x) | (f2bf(b.y) << 16);
  o.w = f2bf(b.z) | (f2bf(b.w) << 16);
  ws[T] = o;
}

// ---------------------------------------------------------------------------
// Dequant 8 elems (2 packed q2 words; 4 crumbs in each low byte) of one group.
// Table entries {-n, a-n, 2a-n, 3a-n}, a = n*2/3 -- bit-identical to the
// fmaf+f2bf reference path.  v_perm_b32 picks the bf16 entry per crumb.
// ---------------------------------------------------------------------------
__device__ __forceinline__ uint4 deq8(uint32_t qx, uint32_t qy, uint32_t tlo,
                                      uint32_t thi) {
  uint32_t s0 = ((qx & 3u) | ((qx & 0xCu) << 14)) * 0x0202u + 0x01000100u;
  uint32_t s1 = (((qx >> 4) & 3u) | ((qx & 0xC0u) << 10)) * 0x0202u + 0x01000100u;
  uint32_t s2 = ((qy & 3u) | ((qy & 0xCu) << 14)) * 0x0202u + 0x01000100u;
  uint32_t s3 = (((qy >> 4) & 3u) | ((qy & 0xC0u) << 10)) * 0x0202u + 0x01000100u;
  uint4 r;
  r.x = __builtin_amdgcn_perm(thi, tlo, s0);
  r.y = __builtin_amdgcn_perm(thi, tlo, s1);
  r.z = __builtin_amdgcn_perm(thi, tlo, s2);
  r.w = __builtin_amdgcn_perm(thi, tlo, s3);
  return r;
}

// ---------------------------------------------------------------------------
// Kernel 2: grid (256,2), 512 threads, 8 waves: 4 consumers + 4 producers.
// ---------------------------------------------------------------------------
__global__ __launch_bounds__(512, 4) void gemm2bit_kernel(
    const uint4*    __restrict__ aws,  // A chunks (see cvt)
    const uint32_t* __restrict__ q2,   // [G][4] packed 2-bit (low byte crumbs)
    const float*    __restrict__ nrm,  // [G] group norms (f32)
    const float*    __restrict__ bias, // [N]
    float*          __restrict__ out)  // [256][16384] fp32
{
  __shared__ uint4 Bb[2][512];  // 8 chunks (ts*4+nb) x 64 slots, dbuf = 16 KiB

  const int tid  = threadIdx.x;
  const int lane = tid & 63;
  const int w    = tid >> 6;    // 0..7
  const int lo4  = lane & 15;
  const int qd   = lane >> 4;
  const int n0   = blockIdx.x * BN;
  const int m0   = blockIdx.y * 128;

  if (w < 4) {
    // ===================== CONSUMER wave (32m x 64n) ======================
    const int cw  = w;
    const int lrs = lane ^ qd;   // swizzled read lane (matches write swizzle)

    // A frag source: m-chunk mb = blockIdx.y*8 + cw*2 + s
    const uint4* pA = aws + (size_t)(blockIdx.y * 8 + cw * 2) * 8192 + lane;

    f32x4 acc[2][4];
#pragma unroll
    for (int s = 0; s < 2; ++s)
#pragma unroll
      for (int u = 0; u < 4; ++u)
        acc[s][u] = (f32x4){0.f, 0.f, 0.f, 0.f};

    uint4 afE[4], afO[4];   // [s*2+ts]
#pragma unroll
    for (int s = 0; s < 2; ++s)
#pragma unroll
      for (int ts = 0; ts < 2; ++ts)
        afE[s * 2 + ts] = pA[(size_t)s * 8192 + ts * 64];
    LDS_BARRIER();   // matches producer prologue barrier

#define CONS_BODY(T, PR, AFC, AFN)                                              \
    do {                                                                        \
      if ((T) + 1 < NT) {                                                       \
        size_t toff = (size_t)((T) + 1) * 128;                                  \
        _Pragma("unroll")                                                       \
        for (int s = 0; s < 2; ++s)                                             \
          _Pragma("unroll")                                                     \
          for (int ts = 0; ts < 2; ++ts)                                        \
            AFN[s * 2 + ts] = pA[(size_t)s * 8192 + toff + ts * 64];            \
      }                                                                         \
      __builtin_amdgcn_s_setprio(1);                                            \
      _Pragma("unroll")                                                         \
      for (int ts = 0; ts < 2; ++ts) {                                          \
        bf16x8 bfv[4];                                                          \
        _Pragma("unroll")                                                       \
        for (int u = 0; u < 4; ++u)                                             \
          bfv[u] = *(const bf16x8*)&Bb[PR][(ts * 4 + u) * 64 + lrs];            \
        _Pragma("unroll")                                                       \
        for (int s = 0; s < 2; ++s) {                                           \
          bf16x8 av = __builtin_bit_cast(bf16x8, AFC[s * 2 + ts]);              \
          _Pragma("unroll")                                                     \
          for (int u = 0; u < 4; ++u)                                           \
            acc[s][u] = __builtin_amdgcn_mfma_f32_16x16x32_bf16(av, bfv[u],     \
                                                            acc[s][u], 0, 0, 0);\
        }                                                                       \
      }                                                                         \
      __builtin_amdgcn_s_setprio(0);                                            \
      LDS_BARRIER();                                                            \
    } while (0)

    for (int t2 = 0; t2 < NT; t2 += 2) {
      CONS_BODY(t2,     0, afE, afO);
      CONS_BODY(t2 + 1, 1, afO, afE);
    }
#undef CONS_BODY

    // epilogue: C/D layout col=lane&15 (n), row=(lane>>4)*4+reg (m)
    float bv[4];
#pragma unroll
    for (int u = 0; u < 4; ++u)
      bv[u] = bias[n0 + u * 16 + lo4];
#pragma unroll
    for (int s = 0; s < 2; ++s) {
      int mrow = m0 + cw * 32 + s * 16 + qd * 4;
#pragma unroll
      for (int u = 0; u < 4; ++u) {
        int ncol = n0 + u * 16 + lo4;
        float* p = out + (size_t)mrow * N_DIM + ncol;
#pragma unroll
        for (int r = 0; r < 4; ++r)
          p[(size_t)r * N_DIM] = acc[s][u][r] + bv[u];
      }
    }
  } else {
    // ===================== PRODUCER wave (16n x 4 groups) =================
    const int pw    = w - 4;        // n-block 0..3
    const int kg    = lane & 3;     // k-group within BK (0..3)
    const int n_loc = lane >> 2;    // 0..15
    const int grow  = n0 + pw * 16 + n_loc;
    // write slots (XOR swizzle phys = logical ^ qd2), chunk cb = (kg>>1)*4+pw
    const int qd2a  = (kg & 1) * 2;
    const int qd2b  = qd2a + 1;
    const int bsA = ((kg >> 1) * 4 + pw) * 64 + qd2a * 16 + (n_loc ^ qd2a);
    const int bsB = ((kg >> 1) * 4 + pw) * 64 + qd2b * 16 + (n_loc ^ qd2b);

    const uint32_t* pq = q2 + ((size_t)grow * 256 + kg) * 4;  // uint4 per body
    const float*    pn = nrm + (size_t)grow * 256 + kg;

    // prologue: dequant tile 0; prefetch q(1)->E, q(2)->O
    uint4 q0 = *(const uint4*)pq;
    float y0 = pn[0];
    uint4 qE = *(const uint4*)(pq + 16);
    float nE = pn[4];
    uint4 qO = *(const uint4*)(pq + 32);
    float nO = pn[8];
    {
      float a2 = y0 * (2.0f / 3.0f);
      uint32_t tlo = f2bf(-y0) | (f2bf(fmaf(1.0f, a2, -y0)) << 16);
      uint32_t thi = f2bf(fmaf(2.0f, a2, -y0)) | (f2bf(fmaf(3.0f, a2, -y0)) << 16);
      Bb[0][bsA] = deq8(q0.x, q0.y, tlo, thi);
      Bb[0][bsB] = deq8(q0.z, q0.w, tlo, thi);
    }
    LDS_BARRIER();

#define PROD_BODY(T, PR, QQ, NN)                                                \
    do {                                                                        \
      if ((T) + 1 < NT) {                                                       \
        float a2 = NN * (2.0f / 3.0f);                                          \
        uint32_t tlo = f2bf(-NN) | (f2bf(fmaf(1.0f, a2, -NN)) << 16);           \
        uint32_t thi = f2bf(fmaf(2.0f, a2, -NN)) |                              \
                       (f2bf(fmaf(3.0f, a2, -NN)) << 16);                       \
        Bb[(PR) ^ 1][bsA] = deq8(QQ.x, QQ.y, tlo, thi);                         \
        Bb[(PR) ^ 1][bsB] = deq8(QQ.z, QQ.w, tlo, thi);                         \
      }                                                                         \
      if ((T) + 3 < NT) {                                                       \
        QQ = *(const uint4*)(pq + (size_t)((T) + 3) * 16);                      \
        NN = pn[(size_t)((T) + 3) * 4];                                         \
      }                                                                         \
      LDS_BARRIER();                                                            \
    } while (0)

    for (int t2 = 0; t2 < NT; t2 += 2) {
      PROD_BODY(t2,     0, qE, nE);
      PROD_BODY(t2 + 1, 1, qO, nO);
    }
#undef PROD_BODY
  }
}

// ---------------------------------------------------------------------------
extern "C" void kernel_launch(void* const* d_in, const int* in_sizes, int n_in,
                              void* d_out, int out_size, void* d_ws, size_t ws_size,
                              hipStream_t stream) {
  const float*    x    = (const float*)d_in[0];
  const uint32_t* q2   = (const uint32_t*)d_in[1];
  const float*    nm   = (const float*)d_in[2];
  const float*    bias = (const float*)d_in[3];
  float*          out  = (float*)d_out;
  uint4*          aws  = (uint4*)d_ws;   // 2 MiB: x as bf16 fragment chunks

  cvt_x_kernel<<<512, 256, 0, stream>>>(x, aws);
  gemm2bit_kernel<<<dim3(N_DIM / BN, 2), 512, 0, stream>>>(aws, q2, nm, bias, out);
}